// Round 2
// baseline (1724.187 us; speedup 1.0000x reference)
//
#include <hip/hip_runtime.h>
#include <hip/hip_bf16.h>

#define NN 20000
#define NE 320000

typedef __hip_bfloat16 bf16;
typedef __attribute__((ext_vector_type(8))) short bf16x8;
typedef __attribute__((ext_vector_type(4))) float f32x4;

static __device__ __forceinline__ float b2f(bf16 x) { return __bfloat162float(x); }

// ---------------- fp32 -> bf16 convert ----------------
__global__ void convert_f32_bf16(const float* __restrict__ in, bf16* __restrict__ out, int n) {
    int i = blockIdx.x * blockDim.x + threadIdx.x;
    if (i < n) out[i] = __float2bfloat16(in[i]);
}

// ---------------- W transpose + convert: WT[dout][din] = bf16(W[din][dout]) ----------------
__global__ void transpose_w(const float* __restrict__ W, bf16* __restrict__ WT,
                            int din, int dout) {
    int i = blockIdx.x * blockDim.x + threadIdx.x;
    if (i >= din * dout) return;
    int r = i / dout, c = i % dout;
    WT[(long)c * din + r] = __float2bfloat16(W[i]);
}

// ---------------- CSR build ----------------
__global__ void hist_kernel(const int* __restrict__ dst, int* __restrict__ counts, int n) {
    int i = blockIdx.x * blockDim.x + threadIdx.x;
    if (i < n) atomicAdd(&counts[dst[i]], 1);
}

// single block, 1024 threads: exclusive scan of counts -> offsets, copy to cursor
__global__ void scan_counts(const int* __restrict__ counts, int* __restrict__ offsets,
                            int* __restrict__ cursor, int n) {
    const int T = 1024;
    int tid = threadIdx.x;
    int per = (n + T - 1) / T;
    int base = tid * per;
    int local = 0;
    for (int i = 0; i < per; i++) {
        int idx = base + i;
        if (idx < n) local += counts[idx];
    }
    __shared__ int sums[T];
    sums[tid] = local;
    __syncthreads();
    for (int s = 1; s < T; s <<= 1) {
        int v = (tid >= s) ? sums[tid - s] : 0;
        __syncthreads();
        sums[tid] += v;
        __syncthreads();
    }
    int run = sums[tid] - local;  // exclusive
    for (int i = 0; i < per; i++) {
        int idx = base + i;
        if (idx < n) {
            offsets[idx] = run;
            cursor[idx] = run;
            run += counts[idx];
        }
    }
    if (tid == T - 1) offsets[n] = run;
}

__global__ void scatter_kernel(const int* __restrict__ dst, int* __restrict__ cursor,
                               int* __restrict__ eid, int n) {
    int i = blockIdx.x * blockDim.x + threadIdx.x;
    if (i < n) {
        int p = atomicAdd(&cursor[dst[i]], 1);
        eid[p] = i;
    }
}

// ---------------- GEMM: H[M,N] = A[M,K] @ W[K,N] via WT[N,K], MFMA 16x16x32 bf16
// wave -> 16x64 output tile; fragments loaded directly from global (cache-fed)
__global__ void gemm_mfma(const bf16* __restrict__ A, const bf16* __restrict__ WT,
                          bf16* __restrict__ H, int M, int K, int N) {
    int wave = (blockIdx.x * blockDim.x + threadIdx.x) >> 6;
    int lane = threadIdx.x & 63;
    int ntiles = N >> 6;
    int rowTile = wave / ntiles;
    int colTile = wave - rowTile * ntiles;
    int row0 = rowTile << 4;
    if (row0 >= M) return;
    int col0 = colTile << 6;
    int m = lane & 15, quad = lane >> 4;

    f32x4 acc0 = {0.f, 0.f, 0.f, 0.f};
    f32x4 acc1 = {0.f, 0.f, 0.f, 0.f};
    f32x4 acc2 = {0.f, 0.f, 0.f, 0.f};
    f32x4 acc3 = {0.f, 0.f, 0.f, 0.f};

    const short* a_base = (const short*)A + (long)(row0 + m) * K + quad * 8;
    const short* b0 = (const short*)WT + (long)(col0 + m) * K + quad * 8;
    const short* b1 = b0 + (long)16 * K;
    const short* b2 = b0 + (long)32 * K;
    const short* b3 = b0 + (long)48 * K;

    for (int k0 = 0; k0 < K; k0 += 32) {
        bf16x8 a = *(const bf16x8*)(a_base + k0);
        bf16x8 vb0 = *(const bf16x8*)(b0 + k0);
        bf16x8 vb1 = *(const bf16x8*)(b1 + k0);
        bf16x8 vb2 = *(const bf16x8*)(b2 + k0);
        bf16x8 vb3 = *(const bf16x8*)(b3 + k0);
        acc0 = __builtin_amdgcn_mfma_f32_16x16x32_bf16(a, vb0, acc0, 0, 0, 0);
        acc1 = __builtin_amdgcn_mfma_f32_16x16x32_bf16(a, vb1, acc1, 0, 0, 0);
        acc2 = __builtin_amdgcn_mfma_f32_16x16x32_bf16(a, vb2, acc2, 0, 0, 0);
        acc3 = __builtin_amdgcn_mfma_f32_16x16x32_bf16(a, vb3, acc3, 0, 0, 0);
    }
    // D layout: row = row0 + quad*4 + r, col = col0 + 16*t + m
    #pragma unroll
    for (int r = 0; r < 4; r++) {
        long row = row0 + quad * 4 + r;
        bf16* out = H + row * N + col0 + m;
        out[0]  = __float2bfloat16(acc0[r]);
        out[16] = __float2bfloat16(acc1[r]);
        out[32] = __float2bfloat16(acc2[r]);
        out[48] = __float2bfloat16(acc3[r]);
    }
}

// ---------------- el/er: one wave per node ----------------
__global__ void compute_elr(const bf16* __restrict__ h, const float* __restrict__ al,
                            const float* __restrict__ ar, float* __restrict__ el,
                            float* __restrict__ er, int dout, int n) {
    int wid = (blockIdx.x * blockDim.x + threadIdx.x) >> 6;
    int lane = threadIdx.x & 63;
    if (wid >= n) return;
    const bf16* row = h + (long)wid * dout;
    float sl = 0.f, sr = 0.f;
    for (int c = lane; c < dout; c += 64) {
        float v = b2f(row[c]);
        sl += v * al[c];
        sr += v * ar[c];
    }
    #pragma unroll
    for (int o = 32; o > 0; o >>= 1) {
        sl += __shfl_down(sl, o);
        sr += __shfl_down(sr, o);
    }
    if (lane == 0) { el[wid] = sl; er[wid] = sr; }
}

// ---------------- edge softmax per destination node (thread-per-node) ----------------
__global__ void edge_softmax(const int* __restrict__ off, const int* __restrict__ eid,
                             const int* __restrict__ src, const float* __restrict__ el,
                             const float* __restrict__ er, float* __restrict__ alpha, int n) {
    int d = blockIdx.x * blockDim.x + threadIdx.x;
    if (d >= n) return;
    int s = off[d], e = off[d + 1];
    if (e <= s) return;
    float erd = er[d];
    float mx = -1e30f;
    for (int j = s; j < e; j++) {
        float v = el[src[eid[j]]] + erd;
        v = v >= 0.f ? v : 0.2f * v;   // leaky_relu
        alpha[j] = v;
        mx = fmaxf(mx, v);
    }
    float ssum = 0.f;
    for (int j = s; j < e; j++) {
        float x = __expf(alpha[j] - mx);
        alpha[j] = x;
        ssum += x;
    }
    float inv = 1.f / ssum;
    for (int j = s; j < e; j++) alpha[j] *= inv;
}

// ---------------- aggregate: block per dst node, fused bias + tanh + bf16 cast
__global__ void aggregate(const bf16* __restrict__ h, const float* __restrict__ alpha,
                          const int* __restrict__ eid, const int* __restrict__ off,
                          const int* __restrict__ src, const float* __restrict__ bias,
                          bf16* __restrict__ xnext, int dout) {
    int d = blockIdx.x;
    int cpt = dout / blockDim.x;   // 1..4
    float acc[4] = {0.f, 0.f, 0.f, 0.f};
    int s = off[d], e = off[d + 1];
    for (int j = s; j < e; j++) {
        float a = alpha[j];
        const bf16* row = h + (long)src[eid[j]] * dout;
        for (int c = 0; c < cpt; c++)
            acc[c] += a * b2f(row[threadIdx.x + c * blockDim.x]);
    }
    for (int c = 0; c < cpt; c++) {
        int ch = threadIdx.x + c * blockDim.x;
        float v = tanhf(acc[c] + bias[ch]);
        xnext[(long)d * dout + ch] = __float2bfloat16(v);
    }
}

// ---------------- mean pooling over first (order+1) rows ----------------
__global__ void pool_mean(const bf16* __restrict__ x, const int* __restrict__ order,
                          float* __restrict__ pooling, int dout) {
    int c = blockIdx.x * blockDim.x + threadIdx.x;
    if (c >= dout) return;
    int rows = order[0] + 1;
    float s = 0.f;
    for (int r = 0; r < rows; r++) s += b2f(x[(long)r * dout + c]);
    pooling[c] = s / (float)rows;
}

// ---------------- head: logits = pooling @ relW + relB; gather by nonzero(rel)
__global__ void final_logits(const float* __restrict__ pooling, const float* __restrict__ relW,
                             const float* __restrict__ relB, const int* __restrict__ rel,
                             float* __restrict__ out, int din, int nout) {
    __shared__ float logits[64];
    __shared__ int nzv[64];
    int t = threadIdx.x;
    if (t < nout) {
        float s = 0.f;
        for (int c = 0; c < din; c++) s += pooling[c] * relW[(long)c * nout + t];
        logits[t] = s + relB[t];
    }
    if (t == 0) {
        int k = 0;
        for (int i = 0; i < nout; i++)
            if (rel[i] != 0) nzv[k++] = i;
        for (; k < nout; k++) nzv[k] = 0;   // jnp.nonzero pads with 0
    }
    __syncthreads();
    if (t < nout) out[t] = logits[nzv[t]];
}

extern "C" void kernel_launch(void* const* d_in, const int* in_sizes, int n_in,
                              void* d_out, int out_size, void* d_ws, size_t ws_size,
                              hipStream_t stream) {
    const float* feat = (const float*)d_in[0];
    const float* W[4]  = {(const float*)d_in[1], (const float*)d_in[5], (const float*)d_in[9],  (const float*)d_in[13]};
    const float* al[4] = {(const float*)d_in[2], (const float*)d_in[6], (const float*)d_in[10], (const float*)d_in[14]};
    const float* ar[4] = {(const float*)d_in[3], (const float*)d_in[7], (const float*)d_in[11], (const float*)d_in[15]};
    const float* bias[4] = {(const float*)d_in[4], (const float*)d_in[8], (const float*)d_in[12], (const float*)d_in[16]};
    const float* relW = (const float*)d_in[17];
    const float* relB = (const float*)d_in[18];
    const int* src = (const int*)d_in[19];
    const int* dst = (const int*)d_in[20];
    const int* rel = (const int*)d_in[21];
    const int* order = (const int*)d_in[22];

    const int dims[5] = {64, 128, 256, 512, 1024};

    // ---- workspace carve (256B aligned) ----
    char* p = (char*)d_ws;
    auto carve = [&](size_t bytes) {
        void* r = (void*)p;
        p += (bytes + 255) & ~(size_t)255;
        return r;
    };
    bf16* xbuf = (bf16*)carve((size_t)NN * 1024 * sizeof(bf16));
    bf16* hbuf = (bf16*)carve((size_t)NN * 1024 * sizeof(bf16));
    bf16* featb = (bf16*)carve((size_t)NN * 64 * sizeof(bf16));
    bf16* wt[4];
    for (int l = 0; l < 4; l++)
        wt[l] = (bf16*)carve((size_t)dims[l] * dims[l + 1] * sizeof(bf16));
    float* el = (float*)carve((size_t)NN * sizeof(float));
    float* er = (float*)carve((size_t)NN * sizeof(float));
    float* alpha = (float*)carve((size_t)NE * sizeof(float));
    int* counts  = (int*)carve((size_t)NN * sizeof(int));
    int* offsets = (int*)carve((size_t)(NN + 1) * sizeof(int));
    int* cursor  = (int*)carve((size_t)NN * sizeof(int));
    int* eid     = (int*)carve((size_t)NE * sizeof(int));
    float* pooling = (float*)carve(1024 * sizeof(float));

    // ---- convert feat, transpose+convert weights ----
    convert_f32_bf16<<<(NN * 64 + 255) / 256, 256, 0, stream>>>(feat, featb, NN * 64);
    for (int l = 0; l < 4; l++) {
        int ne = dims[l] * dims[l + 1];
        transpose_w<<<(ne + 255) / 256, 256, 0, stream>>>(W[l], wt[l], dims[l], dims[l + 1]);
    }

    // ---- CSR by dst ----
    hipMemsetAsync(counts, 0, (size_t)NN * sizeof(int), stream);
    hist_kernel<<<(NE + 255) / 256, 256, 0, stream>>>(dst, counts, NE);
    scan_counts<<<1, 1024, 0, stream>>>(counts, offsets, cursor, NN);
    scatter_kernel<<<(NE + 255) / 256, 256, 0, stream>>>(dst, cursor, eid, NE);

    // ---- 4 GAT layers ----
    const bf16* x = featb;
    for (int l = 0; l < 4; l++) {
        int K = dims[l], N = dims[l + 1];
        int waves = 1250 * (N >> 6);      // ceil(20000/16) row tiles x N/64 col tiles
        gemm_mfma<<<waves / 4, 256, 0, stream>>>(x, wt[l], hbuf, NN, K, N);
        compute_elr<<<(NN * 64) / 256, 256, 0, stream>>>(hbuf, al[l], ar[l], el, er, N, NN);
        edge_softmax<<<(NN + 255) / 256, 256, 0, stream>>>(offsets, eid, src, el, er, alpha, NN);
        int bdim = N < 256 ? N : 256;
        aggregate<<<NN, bdim, 0, stream>>>(hbuf, alpha, eid, offsets, src, bias[l], xbuf, N);
        x = xbuf;
    }

    // ---- head ----
    pool_mean<<<4, 256, 0, stream>>>(xbuf, order, pooling, 1024);
    final_logits<<<1, 64, 0, stream>>>(pooling, relW, relB, rel, (float*)d_out, 1024, 64);
}

// Round 3
// 698.829 us; speedup vs baseline: 2.4673x; 2.4673x over previous
//
#include <hip/hip_runtime.h>
#include <hip/hip_bf16.h>

#define NN 20000
#define NE 320000

typedef __hip_bfloat16 bf16;
typedef __attribute__((ext_vector_type(8))) short bf16x8;
typedef __attribute__((ext_vector_type(4))) float f32x4;

template<int V> struct VecT { typedef short type __attribute__((ext_vector_type(V))); };
template<> struct VecT<1> { typedef short type; };

static __device__ __forceinline__ float b2f(bf16 x) { return __bfloat162float(x); }
static __device__ __forceinline__ float bfbits2f(short s) {
    unsigned int u = ((unsigned int)(unsigned short)s) << 16;
    float f; __builtin_memcpy(&f, &u, 4); return f;
}
static __device__ __forceinline__ short f2bfbits(float v) {
    bf16 h = __float2bfloat16(v);
    short s; __builtin_memcpy(&s, &h, 2); return s;
}

// ---------------- fp32 -> bf16 convert ----------------
__global__ void convert_f32_bf16(const float* __restrict__ in, bf16* __restrict__ out, int n) {
    int i = blockIdx.x * blockDim.x + threadIdx.x;
    if (i < n) out[i] = __float2bfloat16(in[i]);
}

// ---------------- W transpose + convert: WT[dout][din] = bf16(W[din][dout]) ----------------
__global__ void transpose_w(const float* __restrict__ W, bf16* __restrict__ WT,
                            int din, int dout) {
    int i = blockIdx.x * blockDim.x + threadIdx.x;
    if (i >= din * dout) return;
    int r = i / dout, c = i % dout;
    WT[(long)c * din + r] = __float2bfloat16(W[i]);
}

// ---------------- wal = W @ al, war = W @ ar  (fp32, one block per input row)
__global__ void compute_walwar(const float* __restrict__ W, const float* __restrict__ al,
                               const float* __restrict__ ar, float* __restrict__ wal,
                               float* __restrict__ war, int dout) {
    int k = blockIdx.x;
    const float* row = W + (long)k * dout;
    float sl = 0.f, sr = 0.f;
    for (int j = threadIdx.x; j < dout; j += blockDim.x) {
        float w = row[j];
        sl += w * al[j];
        sr += w * ar[j];
    }
    __shared__ float sbl[256], sbr[256];
    sbl[threadIdx.x] = sl; sbr[threadIdx.x] = sr;
    __syncthreads();
    for (int st = 128; st > 0; st >>= 1) {
        if (threadIdx.x < st) {
            sbl[threadIdx.x] += sbl[threadIdx.x + st];
            sbr[threadIdx.x] += sbr[threadIdx.x + st];
        }
        __syncthreads();
    }
    if (threadIdx.x == 0) { wal[k] = sbl[0]; war[k] = sbr[0]; }
}

// ---------------- CSR build ----------------
__global__ void hist_kernel(const int* __restrict__ dst, int* __restrict__ counts, int n) {
    int i = blockIdx.x * blockDim.x + threadIdx.x;
    if (i < n) atomicAdd(&counts[dst[i]], 1);
}

__global__ void scan_counts(const int* __restrict__ counts, int* __restrict__ offsets,
                            int* __restrict__ cursor, int n) {
    const int T = 1024;
    int tid = threadIdx.x;
    int per = (n + T - 1) / T;
    int base = tid * per;
    int local = 0;
    for (int i = 0; i < per; i++) {
        int idx = base + i;
        if (idx < n) local += counts[idx];
    }
    __shared__ int sums[T];
    sums[tid] = local;
    __syncthreads();
    for (int s = 1; s < T; s <<= 1) {
        int v = (tid >= s) ? sums[tid - s] : 0;
        __syncthreads();
        sums[tid] += v;
        __syncthreads();
    }
    int run = sums[tid] - local;  // exclusive
    for (int i = 0; i < per; i++) {
        int idx = base + i;
        if (idx < n) {
            offsets[idx] = run;
            cursor[idx] = run;
            run += counts[idx];
        }
    }
    if (tid == T - 1) offsets[n] = run;
}

// writes src node id directly in CSR order (esrc), no eid indirection needed later
__global__ void scatter_kernel(const int* __restrict__ src, const int* __restrict__ dst,
                               int* __restrict__ cursor, int* __restrict__ esrc, int n) {
    int i = blockIdx.x * blockDim.x + threadIdx.x;
    if (i < n) {
        int p = atomicAdd(&cursor[dst[i]], 1);
        esrc[p] = src[i];
    }
}

// ---------------- el/er directly from X: el = X . wal, er = X . war (wave/node)
template<int V>
__global__ void compute_elr_v(const bf16* __restrict__ X, const float* __restrict__ wal,
                              const float* __restrict__ war, float* __restrict__ el,
                              float* __restrict__ er, int din) {
    typedef typename VecT<V>::type svec;
    int node = (blockIdx.x * blockDim.x + threadIdx.x) >> 6;
    int lane = threadIdx.x & 63;
    if (node >= NN) return;
    svec row = *(const svec*)((const short*)X + (long)node * din + lane * V);
    short tmp[V];
    __builtin_memcpy(tmp, &row, sizeof(row));
    float sl = 0.f, sr = 0.f;
    #pragma unroll
    for (int v = 0; v < V; v++) {
        float x = bfbits2f(tmp[v]);
        sl += x * wal[lane * V + v];
        sr += x * war[lane * V + v];
    }
    #pragma unroll
    for (int o = 32; o > 0; o >>= 1) {
        sl += __shfl_down(sl, o);
        sr += __shfl_down(sr, o);
    }
    if (lane == 0) { el[node] = sl; er[node] = sr; }
}

// ---------------- edge softmax per destination node (thread-per-node) ----------------
__global__ void edge_softmax(const int* __restrict__ off, const int* __restrict__ esrc,
                             const float* __restrict__ el, const float* __restrict__ er,
                             float* __restrict__ alpha, int n) {
    int d = blockIdx.x * blockDim.x + threadIdx.x;
    if (d >= n) return;
    int s = off[d], e = off[d + 1];
    if (e <= s) return;
    float erd = er[d];
    float mx = -1e30f;
    for (int j = s; j < e; j++) {
        float v = el[esrc[j]] + erd;
        v = v >= 0.f ? v : 0.2f * v;   // leaky_relu
        alpha[j] = v;
        mx = fmaxf(mx, v);
    }
    float ssum = 0.f;
    for (int j = s; j < e; j++) {
        float x = __expf(alpha[j] - mx);
        alpha[j] = x;
        ssum += x;
    }
    float inv = 1.f / ssum;
    for (int j = s; j < e; j++) alpha[j] *= inv;
}

// ---------------- Y = A @ X : wave per node, V=din/64 channels per lane ----------------
template<int V>
__global__ void aggregate_x(const bf16* __restrict__ X, const float* __restrict__ alpha,
                            const int* __restrict__ esrc, const int* __restrict__ off,
                            bf16* __restrict__ Y, int din) {
    typedef typename VecT<V>::type svec;
    int node = blockIdx.x * (blockDim.x >> 6) + (threadIdx.x >> 6);
    if (node >= NN) return;
    int lane = threadIdx.x & 63;
    const short* xb = (const short*)X + lane * V;
    float acc[V];
    #pragma unroll
    for (int v = 0; v < V; v++) acc[v] = 0.f;
    int s = off[node], e = off[node + 1];
    float a_nx = 0.f; int r_nx = 0;
    if (s < e) { a_nx = alpha[s]; r_nx = esrc[s]; }
    for (int j = s; j < e; j++) {
        svec row = *(const svec*)(xb + (long)r_nx * din);
        float a = a_nx;
        if (j + 1 < e) { a_nx = alpha[j + 1]; r_nx = esrc[j + 1]; }
        short tmp[V];
        __builtin_memcpy(tmp, &row, sizeof(row));
        #pragma unroll
        for (int v = 0; v < V; v++) acc[v] += a * bfbits2f(tmp[v]);
    }
    short outv[V];
    #pragma unroll
    for (int v = 0; v < V; v++) outv[v] = f2bfbits(acc[v]);
    svec store;
    __builtin_memcpy(&store, outv, sizeof(store));
    *(svec*)((short*)Y + (long)node * din + lane * V) = store;
}

// ---------------- GEMM fused: X_next = tanh(Y @ W + b), MFMA 16x16x32 bf16
__global__ void gemm_fused(const bf16* __restrict__ A, const bf16* __restrict__ WT,
                           const float* __restrict__ bias, bf16* __restrict__ H,
                           int M, int K, int N) {
    int wave = (blockIdx.x * blockDim.x + threadIdx.x) >> 6;
    int lane = threadIdx.x & 63;
    int ntiles = N >> 6;
    int rowTile = wave / ntiles;
    int colTile = wave - rowTile * ntiles;
    int row0 = rowTile << 4;
    if (row0 >= M) return;
    int col0 = colTile << 6;
    int m = lane & 15, quad = lane >> 4;

    f32x4 acc0 = {0.f, 0.f, 0.f, 0.f};
    f32x4 acc1 = {0.f, 0.f, 0.f, 0.f};
    f32x4 acc2 = {0.f, 0.f, 0.f, 0.f};
    f32x4 acc3 = {0.f, 0.f, 0.f, 0.f};

    const short* a_base = (const short*)A + (long)(row0 + m) * K + quad * 8;
    const short* b0 = (const short*)WT + (long)(col0 + m) * K + quad * 8;
    const short* b1 = b0 + (long)16 * K;
    const short* b2 = b0 + (long)32 * K;
    const short* b3 = b0 + (long)48 * K;

    for (int k0 = 0; k0 < K; k0 += 32) {
        bf16x8 a = *(const bf16x8*)(a_base + k0);
        bf16x8 vb0 = *(const bf16x8*)(b0 + k0);
        bf16x8 vb1 = *(const bf16x8*)(b1 + k0);
        bf16x8 vb2 = *(const bf16x8*)(b2 + k0);
        bf16x8 vb3 = *(const bf16x8*)(b3 + k0);
        acc0 = __builtin_amdgcn_mfma_f32_16x16x32_bf16(a, vb0, acc0, 0, 0, 0);
        acc1 = __builtin_amdgcn_mfma_f32_16x16x32_bf16(a, vb1, acc1, 0, 0, 0);
        acc2 = __builtin_amdgcn_mfma_f32_16x16x32_bf16(a, vb2, acc2, 0, 0, 0);
        acc3 = __builtin_amdgcn_mfma_f32_16x16x32_bf16(a, vb3, acc3, 0, 0, 0);
    }
    float bb0 = bias[col0 + m];
    float bb1 = bias[col0 + m + 16];
    float bb2 = bias[col0 + m + 32];
    float bb3 = bias[col0 + m + 48];
    // D layout: row = row0 + quad*4 + r, col = col0 + 16*t + m
    #pragma unroll
    for (int r = 0; r < 4; r++) {
        long row = row0 + quad * 4 + r;
        bf16* out = H + row * N + col0 + m;
        out[0]  = __float2bfloat16(tanhf(acc0[r] + bb0));
        out[16] = __float2bfloat16(tanhf(acc1[r] + bb1));
        out[32] = __float2bfloat16(tanhf(acc2[r] + bb2));
        out[48] = __float2bfloat16(tanhf(acc3[r] + bb3));
    }
}

// ---------------- pool sum: 256 blocks (4 channel groups x 64 row stripes) ----------------
__global__ void pool_sum(const bf16* __restrict__ X, const int* __restrict__ order,
                         float* __restrict__ poolsum) {
    int cg = blockIdx.x & 3, rs = blockIdx.x >> 2;
    int c = cg * 256 + threadIdx.x;
    int rows = order[0] + 1;
    float s = 0.f;
    for (int r = rs; r < rows; r += 64) s += b2f(X[(long)r * 1024 + c]);
    atomicAdd(&poolsum[c], s);
}

// ---------------- head: logits[t] = poolsum . relW[:,t] / rows + relB[t] ----------------
__global__ void head_logits(const float* __restrict__ poolsum, const float* __restrict__ relW,
                            const float* __restrict__ relB, const int* __restrict__ order,
                            float* __restrict__ logits) {
    int t = blockIdx.x;   // 64 blocks
    float s = 0.f;
    for (int c = threadIdx.x; c < 1024; c += 256)
        s += poolsum[c] * relW[(long)c * 64 + t];
    __shared__ float sb[256];
    sb[threadIdx.x] = s;
    __syncthreads();
    for (int st = 128; st > 0; st >>= 1) {
        if (threadIdx.x < st) sb[threadIdx.x] += sb[threadIdx.x + st];
        __syncthreads();
    }
    if (threadIdx.x == 0) {
        float rows = (float)(order[0] + 1);
        logits[t] = sb[0] / rows + relB[t];
    }
}

__global__ void head_gather(const float* __restrict__ logits, const int* __restrict__ rel,
                            float* __restrict__ out) {
    __shared__ int nzv[64];
    int t = threadIdx.x;
    if (t == 0) {
        int k = 0;
        for (int i = 0; i < 64; i++)
            if (rel[i] != 0) nzv[k++] = i;
        for (; k < 64; k++) nzv[k] = 0;   // jnp.nonzero pads with 0
    }
    __syncthreads();
    out[t] = logits[nzv[t]];
}

extern "C" void kernel_launch(void* const* d_in, const int* in_sizes, int n_in,
                              void* d_out, int out_size, void* d_ws, size_t ws_size,
                              hipStream_t stream) {
    const float* feat = (const float*)d_in[0];
    const float* W[4]  = {(const float*)d_in[1], (const float*)d_in[5], (const float*)d_in[9],  (const float*)d_in[13]};
    const float* al[4] = {(const float*)d_in[2], (const float*)d_in[6], (const float*)d_in[10], (const float*)d_in[14]};
    const float* ar[4] = {(const float*)d_in[3], (const float*)d_in[7], (const float*)d_in[11], (const float*)d_in[15]};
    const float* bias[4] = {(const float*)d_in[4], (const float*)d_in[8], (const float*)d_in[12], (const float*)d_in[16]};
    const float* relW = (const float*)d_in[17];
    const float* relB = (const float*)d_in[18];
    const int* src = (const int*)d_in[19];
    const int* dst = (const int*)d_in[20];
    const int* rel = (const int*)d_in[21];
    const int* order = (const int*)d_in[22];

    const int dims[5] = {64, 128, 256, 512, 1024};

    // ---- workspace carve (256B aligned) ----
    char* p = (char*)d_ws;
    auto carve = [&](size_t bytes) {
        void* r = (void*)p;
        p += (bytes + 255) & ~(size_t)255;
        return r;
    };
    bf16* xbuf = (bf16*)carve((size_t)NN * 1024 * sizeof(bf16));  // layer outputs (max dout=1024)
    bf16* ybuf = (bf16*)carve((size_t)NN * 512 * sizeof(bf16));   // aggregated input (max din=512)
    bf16* featb = (bf16*)carve((size_t)NN * 64 * sizeof(bf16));
    bf16* wt[4];
    for (int l = 0; l < 4; l++)
        wt[l] = (bf16*)carve((size_t)dims[l] * dims[l + 1] * sizeof(bf16));
    float* walbuf = (float*)carve(4 * 512 * sizeof(float));
    float* warbuf = (float*)carve(4 * 512 * sizeof(float));
    float* el = (float*)carve((size_t)NN * sizeof(float));
    float* er = (float*)carve((size_t)NN * sizeof(float));
    float* alpha = (float*)carve((size_t)NE * sizeof(float));
    int* counts  = (int*)carve((size_t)NN * sizeof(int));
    int* offsets = (int*)carve((size_t)(NN + 1) * sizeof(int));
    int* cursor  = (int*)carve((size_t)NN * sizeof(int));
    int* esrc    = (int*)carve((size_t)NE * sizeof(int));
    float* poolsum = (float*)carve(1024 * sizeof(float));
    float* logits  = (float*)carve(64 * sizeof(float));

    // ---- convert feat, transpose+convert weights, wal/war ----
    convert_f32_bf16<<<(NN * 64 + 255) / 256, 256, 0, stream>>>(feat, featb, NN * 64);
    for (int l = 0; l < 4; l++) {
        int ne = dims[l] * dims[l + 1];
        transpose_w<<<(ne + 255) / 256, 256, 0, stream>>>(W[l], wt[l], dims[l], dims[l + 1]);
        compute_walwar<<<dims[l], 256, 0, stream>>>(W[l], al[l], ar[l],
                                                    walbuf + l * 512, warbuf + l * 512, dims[l + 1]);
    }

    // ---- CSR by dst (esrc = src ids in CSR order) ----
    hipMemsetAsync(counts, 0, (size_t)NN * sizeof(int), stream);
    hist_kernel<<<(NE + 255) / 256, 256, 0, stream>>>(dst, counts, NE);
    scan_counts<<<1, 1024, 0, stream>>>(counts, offsets, cursor, NN);
    scatter_kernel<<<(NE + 255) / 256, 256, 0, stream>>>(src, dst, cursor, esrc, NE);

    // ---- 4 GAT layers: X_next = tanh((A @ X) @ W + b) ----
    const bf16* x = featb;
    for (int l = 0; l < 4; l++) {
        int K = dims[l], N = dims[l + 1];
        float* wal = walbuf + l * 512;
        float* war = warbuf + l * 512;
        // el/er from X directly
        switch (K) {
            case 64:  compute_elr_v<1><<<5000, 256, 0, stream>>>(x, wal, war, el, er, K); break;
            case 128: compute_elr_v<2><<<5000, 256, 0, stream>>>(x, wal, war, el, er, K); break;
            case 256: compute_elr_v<4><<<5000, 256, 0, stream>>>(x, wal, war, el, er, K); break;
            default:  compute_elr_v<8><<<5000, 256, 0, stream>>>(x, wal, war, el, er, K); break;
        }
        edge_softmax<<<(NN + 255) / 256, 256, 0, stream>>>(offsets, esrc, el, er, alpha, NN);
        switch (K) {
            case 64:  aggregate_x<1><<<5000, 256, 0, stream>>>(x, alpha, esrc, offsets, ybuf, K); break;
            case 128: aggregate_x<2><<<5000, 256, 0, stream>>>(x, alpha, esrc, offsets, ybuf, K); break;
            case 256: aggregate_x<4><<<5000, 256, 0, stream>>>(x, alpha, esrc, offsets, ybuf, K); break;
            default:  aggregate_x<8><<<5000, 256, 0, stream>>>(x, alpha, esrc, offsets, ybuf, K); break;
        }
        int waves = 1250 * (N >> 6);
        gemm_fused<<<waves / 4, 256, 0, stream>>>(ybuf, wt[l], bias[l], xbuf, NN, K, N);
        x = xbuf;
    }

    // ---- head ----
    hipMemsetAsync(poolsum, 0, 1024 * sizeof(float), stream);
    pool_sum<<<256, 256, 0, stream>>>(xbuf, order, poolsum);
    head_logits<<<64, 256, 0, stream>>>(poolsum, relW, relB, order, logits);
    head_gather<<<1, 64, 0, stream>>>(logits, rel, (float*)d_out);
}

// Round 4
// 576.053 us; speedup vs baseline: 2.9931x; 1.2131x over previous
//
#include <hip/hip_runtime.h>
#include <hip/hip_bf16.h>

#define NN 20000
#define NE 320000
#define MPAD 20096   // 157 * 128

typedef __hip_bfloat16 bf16;
typedef __attribute__((ext_vector_type(8))) short bf16x8;
typedef __attribute__((ext_vector_type(4))) float f32x4;

template<int V> struct VecT { typedef short type __attribute__((ext_vector_type(V))); };
template<> struct VecT<1> { typedef short type; };

static __device__ __forceinline__ float b2f(bf16 x) { return __bfloat162float(x); }
static __device__ __forceinline__ float bfbits2f(short s) {
    unsigned int u = ((unsigned int)(unsigned short)s) << 16;
    float f; __builtin_memcpy(&f, &u, 4); return f;
}
static __device__ __forceinline__ short f2bfbits(float v) {
    bf16 h = __float2bfloat16(v);
    short s; __builtin_memcpy(&s, &h, 2); return s;
}

// ---------------- fp32 -> bf16 convert ----------------
__global__ void convert_f32_bf16(const float* __restrict__ in, bf16* __restrict__ out, int n) {
    int i = blockIdx.x * blockDim.x + threadIdx.x;
    if (i < n) out[i] = __float2bfloat16(in[i]);
}

// ---------------- W transpose + convert: WT[dout][din] = bf16(W[din][dout]) ----------------
__global__ void transpose_w(const float* __restrict__ W, bf16* __restrict__ WT,
                            int din, int dout) {
    int i = blockIdx.x * blockDim.x + threadIdx.x;
    if (i >= din * dout) return;
    int r = i / dout, c = i % dout;
    WT[(long)c * din + r] = __float2bfloat16(W[i]);
}

// ---------------- wal = W @ al, war = W @ ar  (fp32, one block per input row)
__global__ void compute_walwar(const float* __restrict__ W, const float* __restrict__ al,
                               const float* __restrict__ ar, float* __restrict__ wal,
                               float* __restrict__ war, int dout) {
    int k = blockIdx.x;
    const float* row = W + (long)k * dout;
    float sl = 0.f, sr = 0.f;
    for (int j = threadIdx.x; j < dout; j += blockDim.x) {
        float w = row[j];
        sl += w * al[j];
        sr += w * ar[j];
    }
    __shared__ float sbl[256], sbr[256];
    sbl[threadIdx.x] = sl; sbr[threadIdx.x] = sr;
    __syncthreads();
    for (int st = 128; st > 0; st >>= 1) {
        if (threadIdx.x < st) {
            sbl[threadIdx.x] += sbl[threadIdx.x + st];
            sbr[threadIdx.x] += sbr[threadIdx.x + st];
        }
        __syncthreads();
    }
    if (threadIdx.x == 0) { wal[k] = sbl[0]; war[k] = sbr[0]; }
}

// ---------------- CSR build ----------------
__global__ void hist_kernel(const int* __restrict__ dst, int* __restrict__ counts, int n) {
    int i = blockIdx.x * blockDim.x + threadIdx.x;
    if (i < n) atomicAdd(&counts[dst[i]], 1);
}

__global__ void scan_counts(const int* __restrict__ counts, int* __restrict__ offsets,
                            int* __restrict__ cursor, int n) {
    const int T = 1024;
    int tid = threadIdx.x;
    int per = (n + T - 1) / T;
    int base = tid * per;
    int local = 0;
    for (int i = 0; i < per; i++) {
        int idx = base + i;
        if (idx < n) local += counts[idx];
    }
    __shared__ int sums[T];
    sums[tid] = local;
    __syncthreads();
    for (int s = 1; s < T; s <<= 1) {
        int v = (tid >= s) ? sums[tid - s] : 0;
        __syncthreads();
        sums[tid] += v;
        __syncthreads();
    }
    int run = sums[tid] - local;  // exclusive
    for (int i = 0; i < per; i++) {
        int idx = base + i;
        if (idx < n) {
            offsets[idx] = run;
            cursor[idx] = run;
            run += counts[idx];
        }
    }
    if (tid == T - 1) offsets[n] = run;
}

// writes src node id directly in CSR order (esrc)
__global__ void scatter_kernel(const int* __restrict__ src, const int* __restrict__ dst,
                               int* __restrict__ cursor, int* __restrict__ esrc, int n) {
    int i = blockIdx.x * blockDim.x + threadIdx.x;
    if (i < n) {
        int p = atomicAdd(&cursor[dst[i]], 1);
        esrc[p] = src[i];
    }
}

// ---------------- counting sort of nodes by degree (single block) ----------------
// Order within a degree bucket is nondeterministic but irrelevant: each node's own
// accumulation order (CSR order) is unchanged, so results are bit-identical.
__global__ void degree_sort(const int* __restrict__ counts, int* __restrict__ nodeperm) {
    __shared__ int h[256];
    __shared__ int cur[256];
    int t = threadIdx.x;
    h[t] = 0;
    __syncthreads();
    for (int i = t; i < NN; i += 256) {
        int d = counts[i]; if (d > 255) d = 255;
        atomicAdd(&h[d], 1);
    }
    __syncthreads();
    int v = h[t];
    __syncthreads();
    for (int st = 1; st < 256; st <<= 1) {
        int u = (t >= st) ? h[t - st] : 0;
        __syncthreads();
        h[t] += u;
        __syncthreads();
    }
    cur[t] = h[t] - v;   // exclusive prefix
    __syncthreads();
    for (int i = t; i < NN; i += 256) {
        int d = counts[i]; if (d > 255) d = 255;
        int p = atomicAdd(&cur[d], 1);
        nodeperm[p] = i;
    }
}

// ---------------- el/er directly from X: el = X . wal, er = X . war (wave/node)
template<int V>
__global__ void compute_elr_v(const bf16* __restrict__ X, const float* __restrict__ wal,
                              const float* __restrict__ war, float* __restrict__ el,
                              float* __restrict__ er, int din) {
    typedef typename VecT<V>::type svec;
    int node = (blockIdx.x * blockDim.x + threadIdx.x) >> 6;
    int lane = threadIdx.x & 63;
    if (node >= NN) return;
    svec row = *(const svec*)((const short*)X + (long)node * din + lane * V);
    short tmp[V];
    __builtin_memcpy(tmp, &row, sizeof(row));
    float sl = 0.f, sr = 0.f;
    #pragma unroll
    for (int v = 0; v < V; v++) {
        float x = bfbits2f(tmp[v]);
        sl += x * wal[lane * V + v];
        sr += x * war[lane * V + v];
    }
    #pragma unroll
    for (int o = 32; o > 0; o >>= 1) {
        sl += __shfl_down(sl, o);
        sr += __shfl_down(sr, o);
    }
    if (lane == 0) { el[node] = sl; er[node] = sr; }
}

// ---------------- edge softmax per destination node (thread-per-node) ----------------
__global__ void edge_softmax(const int* __restrict__ off, const int* __restrict__ esrc,
                             const float* __restrict__ el, const float* __restrict__ er,
                             float* __restrict__ alpha, int n) {
    int d = blockIdx.x * blockDim.x + threadIdx.x;
    if (d >= n) return;
    int s = off[d], e = off[d + 1];
    if (e <= s) return;
    float erd = er[d];
    float mx = -1e30f;
    for (int j = s; j < e; j++) {
        float v = el[esrc[j]] + erd;
        v = v >= 0.f ? v : 0.2f * v;   // leaky_relu
        alpha[j] = v;
        mx = fmaxf(mx, v);
    }
    float ssum = 0.f;
    for (int j = s; j < e; j++) {
        float x = __expf(alpha[j] - mx);
        alpha[j] = x;
        ssum += x;
    }
    float inv = 1.f / ssum;
    for (int j = s; j < e; j++) alpha[j] *= inv;
}

// ---------------- Y = A @ X, small din (64): wave per node, 2B/lane ----------------
__global__ void aggregate_x1(const bf16* __restrict__ X, const float* __restrict__ alpha,
                             const int* __restrict__ esrc, const int* __restrict__ off,
                             bf16* __restrict__ Y, int din) {
    int node = blockIdx.x * (blockDim.x >> 6) + (threadIdx.x >> 6);
    if (node >= NN) return;
    int lane = threadIdx.x & 63;
    const short* xb = (const short*)X + lane;
    float acc = 0.f;
    int s = off[node], e = off[node + 1];
    float a_nx = 0.f; int r_nx = 0;
    if (s < e) { a_nx = alpha[s]; r_nx = esrc[s]; }
    for (int j = s; j < e; j++) {
        float a = a_nx; int r = r_nx;
        if (j + 1 < e) { a_nx = alpha[j + 1]; r_nx = esrc[j + 1]; }
        acc += a * bfbits2f(xb[(long)r * din]);
    }
    *((short*)Y + (long)node * din + lane) = f2bfbits(acc);
}

// ---------------- Y = A @ X, chunked: quarter-wave (16 lanes x 16B) per (node,chunk)
// chunk = 128 channels; chunk-major grid order keeps each XCD's L2 on one chunk.
__global__ void aggregate_q(const bf16* __restrict__ X, const float* __restrict__ alpha,
                            const int* __restrict__ esrc, const int* __restrict__ off,
                            const int* __restrict__ perm, bf16* __restrict__ Y,
                            int din, int nodeBlocks) {
    int chunk = blockIdx.x / nodeBlocks;
    int nb = blockIdx.x - chunk * nodeBlocks;
    int qw = threadIdx.x >> 4, ql = threadIdx.x & 15;
    int slot = nb * 16 + qw;
    if (slot >= NN) return;
    int node = perm[slot];      // degree-sorted: quarter-waves in a wave have ~equal degree
    const short* xb = (const short*)X + chunk * 128 + ql * 8;
    float acc[8] = {0.f,0.f,0.f,0.f,0.f,0.f,0.f,0.f};
    int s = off[node], e = off[node + 1];
    float a_nx = 0.f; int r_nx = 0;
    if (s < e) { a_nx = alpha[s]; r_nx = esrc[s]; }
    for (int j = s; j < e; j++) {
        float a = a_nx; int r = r_nx;
        if (j + 1 < e) { a_nx = alpha[j + 1]; r_nx = esrc[j + 1]; }
        bf16x8 row = *(const bf16x8*)(xb + (long)r * din);
        #pragma unroll
        for (int v = 0; v < 8; v++) acc[v] += a * bfbits2f(row[v]);
    }
    short outv[8];
    #pragma unroll
    for (int v = 0; v < 8; v++) outv[v] = f2bfbits(acc[v]);
    bf16x8 store;
    __builtin_memcpy(&store, outv, sizeof(store));
    *(bf16x8*)((short*)Y + (long)node * din + chunk * 128 + ql * 8) = store;
}

// ---------------- tiled GEMM (m97 structure): X_next = tanh(Y @ W + b)
// block = 256 thr (4 waves), tile 128x128, BK=32, global_load_lds width 16.
// A rows may extend past M into pad rows (buffers sized MPAD) — stores guarded.
__global__ __launch_bounds__(256, 2)
void gemm_tiled(const bf16* __restrict__ A, const bf16* __restrict__ WT,
                const float* __restrict__ bias, bf16* __restrict__ C,
                int M, int K, int N, int ncols) {
    __shared__ short As[4096];   // 128 rows x 32 (K-contig), 8 KB
    __shared__ short Bs[4096];
    int rowTile = blockIdx.x / ncols, colTile = blockIdx.x - rowTile * ncols;
    int row0 = rowTile << 7, col0 = colTile << 7;
    int tid = threadIdx.x;
    int lane = tid & 63, wave = tid >> 6;
    int wr = (wave >> 1) << 6;   // wave's 64-row quadrant
    int wc = (wave & 1) << 6;    // wave's 64-col quadrant
    int m = lane & 15, quad = lane >> 4;

    f32x4 acc[4][4];
    #pragma unroll
    for (int i = 0; i < 4; i++)
        #pragma unroll
        for (int j = 0; j < 4; j++) acc[i][j] = (f32x4){0.f, 0.f, 0.f, 0.f};

    // staging: 512 chunks of 16B per tile; thread t handles chunks t and t+256.
    // chunk i -> row i>>2, col (i&3)*8; LDS offset i*16B (= wave base + lane*16) ✓
    int r1 = tid >> 2, c1 = (tid & 3) << 3;
    int r2 = r1 + 64;
    const short* Ab = (const short*)A;
    const short* Bb = (const short*)WT;
    long ga1 = (long)(row0 + r1) * K + c1;
    long ga2 = (long)(row0 + r2) * K + c1;
    long gb1 = (long)(col0 + r1) * K + c1;
    long gb2 = (long)(col0 + r2) * K + c1;

    typedef const __attribute__((address_space(1))) void cgvoid;
    typedef __attribute__((address_space(3))) void lvoid;

    for (int k0 = 0; k0 < K; k0 += 32) {
        __syncthreads();
        __builtin_amdgcn_global_load_lds((cgvoid*)(Ab + ga1 + k0), (lvoid*)(As + tid * 8),        16, 0, 0);
        __builtin_amdgcn_global_load_lds((cgvoid*)(Ab + ga2 + k0), (lvoid*)(As + 2048 + tid * 8), 16, 0, 0);
        __builtin_amdgcn_global_load_lds((cgvoid*)(Bb + gb1 + k0), (lvoid*)(Bs + tid * 8),        16, 0, 0);
        __builtin_amdgcn_global_load_lds((cgvoid*)(Bb + gb2 + k0), (lvoid*)(Bs + 2048 + tid * 8), 16, 0, 0);
        __syncthreads();
        bf16x8 af[4], bfr[4];
        #pragma unroll
        for (int s = 0; s < 4; s++) {
            af[s]  = *(const bf16x8*)(As + (wr + s * 16 + m) * 32 + quad * 8);
            bfr[s] = *(const bf16x8*)(Bs + (wc + s * 16 + m) * 32 + quad * 8);
        }
        #pragma unroll
        for (int i = 0; i < 4; i++)
            #pragma unroll
            for (int j = 0; j < 4; j++)
                acc[i][j] = __builtin_amdgcn_mfma_f32_16x16x32_bf16(af[i], bfr[j], acc[i][j], 0, 0, 0);
    }
    // epilogue: D row = quad*4 + reg, col = m (within each 16x16)
    #pragma unroll
    for (int j = 0; j < 4; j++) {
        int col = col0 + wc + j * 16 + m;
        float bb = bias[col];
        #pragma unroll
        for (int i = 0; i < 4; i++) {
            int rowb = row0 + wr + i * 16 + quad * 4;
            #pragma unroll
            for (int r = 0; r < 4; r++) {
                int row = rowb + r;
                if (row < M)
                    C[(long)row * N + col] = __float2bfloat16(tanhf(acc[i][j][r] + bb));
            }
        }
    }
}

// ---------------- pool sum: 256 blocks (4 channel groups x 64 row stripes) ----------------
__global__ void pool_sum(const bf16* __restrict__ X, const int* __restrict__ order,
                         float* __restrict__ poolsum) {
    int cg = blockIdx.x & 3, rs = blockIdx.x >> 2;
    int c = cg * 256 + threadIdx.x;
    int rows = order[0] + 1;
    float s = 0.f;
    for (int r = rs; r < rows; r += 64) s += b2f(X[(long)r * 1024 + c]);
    atomicAdd(&poolsum[c], s);
}

// ---------------- head ----------------
__global__ void head_logits(const float* __restrict__ poolsum, const float* __restrict__ relW,
                            const float* __restrict__ relB, const int* __restrict__ order,
                            float* __restrict__ logits) {
    int t = blockIdx.x;   // 64 blocks
    float s = 0.f;
    for (int c = threadIdx.x; c < 1024; c += 256)
        s += poolsum[c] * relW[(long)c * 64 + t];
    __shared__ float sb[256];
    sb[threadIdx.x] = s;
    __syncthreads();
    for (int st = 128; st > 0; st >>= 1) {
        if (threadIdx.x < st) sb[threadIdx.x] += sb[threadIdx.x + st];
        __syncthreads();
    }
    if (threadIdx.x == 0) {
        float rows = (float)(order[0] + 1);
        logits[t] = sb[0] / rows + relB[t];
    }
}

__global__ void head_gather(const float* __restrict__ logits, const int* __restrict__ rel,
                            float* __restrict__ out) {
    __shared__ int nzv[64];
    int t = threadIdx.x;
    if (t == 0) {
        int k = 0;
        for (int i = 0; i < 64; i++)
            if (rel[i] != 0) nzv[k++] = i;
        for (; k < 64; k++) nzv[k] = 0;   // jnp.nonzero pads with 0
    }
    __syncthreads();
    out[t] = logits[nzv[t]];
}

extern "C" void kernel_launch(void* const* d_in, const int* in_sizes, int n_in,
                              void* d_out, int out_size, void* d_ws, size_t ws_size,
                              hipStream_t stream) {
    const float* feat = (const float*)d_in[0];
    const float* W[4]  = {(const float*)d_in[1], (const float*)d_in[5], (const float*)d_in[9],  (const float*)d_in[13]};
    const float* al[4] = {(const float*)d_in[2], (const float*)d_in[6], (const float*)d_in[10], (const float*)d_in[14]};
    const float* ar[4] = {(const float*)d_in[3], (const float*)d_in[7], (const float*)d_in[11], (const float*)d_in[15]};
    const float* bias[4] = {(const float*)d_in[4], (const float*)d_in[8], (const float*)d_in[12], (const float*)d_in[16]};
    const float* relW = (const float*)d_in[17];
    const float* relB = (const float*)d_in[18];
    const int* src = (const int*)d_in[19];
    const int* dst = (const int*)d_in[20];
    const int* rel = (const int*)d_in[21];
    const int* order = (const int*)d_in[22];

    const int dims[5] = {64, 128, 256, 512, 1024};

    // ---- workspace carve (256B aligned); row dim padded to MPAD for GEMM tiles ----
    char* p = (char*)d_ws;
    auto carve = [&](size_t bytes) {
        void* r = (void*)p;
        p += (bytes + 255) & ~(size_t)255;
        return r;
    };
    bf16* xbuf = (bf16*)carve((size_t)MPAD * 1024 * sizeof(bf16));  // layer outputs
    bf16* ybuf = (bf16*)carve((size_t)MPAD * 512 * sizeof(bf16));   // aggregated input
    bf16* featb = (bf16*)carve((size_t)MPAD * 64 * sizeof(bf16));
    bf16* wt[4];
    for (int l = 0; l < 4; l++)
        wt[l] = (bf16*)carve((size_t)dims[l] * dims[l + 1] * sizeof(bf16));
    float* walbuf = (float*)carve(4 * 512 * sizeof(float));
    float* warbuf = (float*)carve(4 * 512 * sizeof(float));
    float* el = (float*)carve((size_t)NN * sizeof(float));
    float* er = (float*)carve((size_t)NN * sizeof(float));
    float* alpha = (float*)carve((size_t)NE * sizeof(float));
    int* counts  = (int*)carve((size_t)NN * sizeof(int));
    int* offsets = (int*)carve((size_t)(NN + 1) * sizeof(int));
    int* cursor  = (int*)carve((size_t)NN * sizeof(int));
    int* esrc    = (int*)carve((size_t)NE * sizeof(int));
    int* nodeperm = (int*)carve((size_t)NN * sizeof(int));
    float* poolsum = (float*)carve(1024 * sizeof(float));
    float* logits  = (float*)carve(64 * sizeof(float));

    // ---- convert feat, transpose+convert weights, wal/war ----
    convert_f32_bf16<<<(NN * 64 + 255) / 256, 256, 0, stream>>>(feat, featb, NN * 64);
    for (int l = 0; l < 4; l++) {
        int ne = dims[l] * dims[l + 1];
        transpose_w<<<(ne + 255) / 256, 256, 0, stream>>>(W[l], wt[l], dims[l], dims[l + 1]);
        compute_walwar<<<dims[l], 256, 0, stream>>>(W[l], al[l], ar[l],
                                                    walbuf + l * 512, warbuf + l * 512, dims[l + 1]);
    }

    // ---- CSR by dst + degree-sorted node permutation ----
    hipMemsetAsync(counts, 0, (size_t)NN * sizeof(int), stream);
    hist_kernel<<<(NE + 255) / 256, 256, 0, stream>>>(dst, counts, NE);
    scan_counts<<<1, 1024, 0, stream>>>(counts, offsets, cursor, NN);
    scatter_kernel<<<(NE + 255) / 256, 256, 0, stream>>>(src, dst, cursor, esrc, NE);
    degree_sort<<<1, 256, 0, stream>>>(counts, nodeperm);

    // ---- 4 GAT layers: X_next = tanh((A @ X) @ W + b) ----
    const bf16* x = featb;
    const int nodeBlocks = NN / 16;   // 1250
    for (int l = 0; l < 4; l++) {
        int K = dims[l], N = dims[l + 1];
        float* wal = walbuf + l * 512;
        float* war = warbuf + l * 512;
        switch (K) {
            case 64:  compute_elr_v<1><<<5000, 256, 0, stream>>>(x, wal, war, el, er, K); break;
            case 128: compute_elr_v<2><<<5000, 256, 0, stream>>>(x, wal, war, el, er, K); break;
            case 256: compute_elr_v<4><<<5000, 256, 0, stream>>>(x, wal, war, el, er, K); break;
            default:  compute_elr_v<8><<<5000, 256, 0, stream>>>(x, wal, war, el, er, K); break;
        }
        edge_softmax<<<(NN + 255) / 256, 256, 0, stream>>>(offsets, esrc, el, er, alpha, NN);
        if (K == 64) {
            aggregate_x1<<<5000, 256, 0, stream>>>(x, alpha, esrc, offsets, ybuf, K);
        } else {
            int chunks = K / 128;
            aggregate_q<<<chunks * nodeBlocks, 256, 0, stream>>>(x, alpha, esrc, offsets,
                                                                 nodeperm, ybuf, K, nodeBlocks);
        }
        int ncols = N >> 7;
        gemm_tiled<<<157 * ncols, 256, 0, stream>>>(ybuf, wt[l], bias[l], xbuf, NN, K, N, ncols);
        x = xbuf;
    }

    // ---- head ----
    hipMemsetAsync(poolsum, 0, 1024 * sizeof(float), stream);
    pool_sum<<<256, 256, 0, stream>>>(xbuf, order, poolsum);
    head_logits<<<64, 256, 0, stream>>>(poolsum, relW, relB, rel ? order : order, logits);
    head_gather<<<1, 64, 0, stream>>>(logits, rel, (float*)d_out);
}

// Round 5
// 542.562 us; speedup vs baseline: 3.1779x; 1.0617x over previous
//
#include <hip/hip_runtime.h>
#include <hip/hip_bf16.h>

#define NN 20000
#define NE 320000
#define MPAD 20096   // 157 * 128

typedef __hip_bfloat16 bf16;
typedef __attribute__((ext_vector_type(8))) short bf16x8;
typedef __attribute__((ext_vector_type(4))) float f32x4;

template<int V> struct VecT { typedef short type __attribute__((ext_vector_type(V))); };
template<> struct VecT<1> { typedef short type; };

static __device__ __forceinline__ float b2f(bf16 x) { return __bfloat162float(x); }
static __device__ __forceinline__ float bfbits2f(short s) {
    unsigned int u = ((unsigned int)(unsigned short)s) << 16;
    float f; __builtin_memcpy(&f, &u, 4); return f;
}
static __device__ __forceinline__ short f2bfbits(float v) {
    bf16 h = __float2bfloat16(v);
    short s; __builtin_memcpy(&s, &h, 2); return s;
}
static __device__ __forceinline__ unsigned short f2bfu(float v) {
    bf16 h = __float2bfloat16(v);
    unsigned short s; __builtin_memcpy(&s, &h, 2); return s;
}

// ---------------- fp32 -> bf16 convert ----------------
__global__ void convert_f32_bf16(const float* __restrict__ in, bf16* __restrict__ out, int n) {
    int i = blockIdx.x * blockDim.x + threadIdx.x;
    if (i < n) out[i] = __float2bfloat16(in[i]);
}

// ---------------- W transpose + convert: WT[dout][din] = bf16(W[din][dout]) ----------------
__global__ void transpose_w(const float* __restrict__ W, bf16* __restrict__ WT,
                            int din, int dout) {
    int i = blockIdx.x * blockDim.x + threadIdx.x;
    if (i >= din * dout) return;
    int r = i / dout, c = i % dout;
    WT[(long)c * din + r] = __float2bfloat16(W[i]);
}

// ---------------- wal = W @ al, war = W @ ar ----------------
__global__ void compute_walwar(const float* __restrict__ W, const float* __restrict__ al,
                               const float* __restrict__ ar, float* __restrict__ wal,
                               float* __restrict__ war, int dout) {
    int k = blockIdx.x;
    const float* row = W + (long)k * dout;
    float sl = 0.f, sr = 0.f;
    for (int j = threadIdx.x; j < dout; j += blockDim.x) {
        float w = row[j];
        sl += w * al[j];
        sr += w * ar[j];
    }
    __shared__ float sbl[256], sbr[256];
    sbl[threadIdx.x] = sl; sbr[threadIdx.x] = sr;
    __syncthreads();
    for (int st = 128; st > 0; st >>= 1) {
        if (threadIdx.x < st) {
            sbl[threadIdx.x] += sbl[threadIdx.x + st];
            sbr[threadIdx.x] += sbr[threadIdx.x + st];
        }
        __syncthreads();
    }
    if (threadIdx.x == 0) { wal[k] = sbl[0]; war[k] = sbr[0]; }
}

// ---------------- CSR build ----------------
__global__ void hist_kernel(const int* __restrict__ dst, int* __restrict__ counts, int n) {
    int i = blockIdx.x * blockDim.x + threadIdx.x;
    if (i < n) atomicAdd(&counts[dst[i]], 1);
}

__global__ void scan_counts(const int* __restrict__ counts, int* __restrict__ offsets,
                            int* __restrict__ cursor, int n) {
    const int T = 1024;
    int tid = threadIdx.x;
    int per = (n + T - 1) / T;
    int base = tid * per;
    int local = 0;
    for (int i = 0; i < per; i++) {
        int idx = base + i;
        if (idx < n) local += counts[idx];
    }
    __shared__ int sums[T];
    sums[tid] = local;
    __syncthreads();
    for (int s = 1; s < T; s <<= 1) {
        int v = (tid >= s) ? sums[tid - s] : 0;
        __syncthreads();
        sums[tid] += v;
        __syncthreads();
    }
    int run = sums[tid] - local;  // exclusive
    for (int i = 0; i < per; i++) {
        int idx = base + i;
        if (idx < n) {
            offsets[idx] = run;
            cursor[idx] = run;
            run += counts[idx];
        }
    }
    if (tid == T - 1) offsets[n] = run;
}

__global__ void scatter_kernel(const int* __restrict__ src, const int* __restrict__ dst,
                               int* __restrict__ cursor, int* __restrict__ esrc, int n) {
    int i = blockIdx.x * blockDim.x + threadIdx.x;
    if (i < n) {
        int p = atomicAdd(&cursor[dst[i]], 1);
        esrc[p] = src[i];
    }
}

// ---------------- counting sort of nodes by degree (single block) ----------------
__global__ void degree_sort(const int* __restrict__ counts, int* __restrict__ nodeperm) {
    __shared__ int h[256];
    __shared__ int cur[256];
    int t = threadIdx.x;
    h[t] = 0;
    __syncthreads();
    for (int i = t; i < NN; i += 256) {
        int d = counts[i]; if (d > 255) d = 255;
        atomicAdd(&h[d], 1);
    }
    __syncthreads();
    int v = h[t];
    __syncthreads();
    for (int st = 1; st < 256; st <<= 1) {
        int u = (t >= st) ? h[t - st] : 0;
        __syncthreads();
        h[t] += u;
        __syncthreads();
    }
    cur[t] = h[t] - v;
    __syncthreads();
    for (int i = t; i < NN; i += 256) {
        int d = counts[i]; if (d > 255) d = 255;
        int p = atomicAdd(&cur[d], 1);
        nodeperm[p] = i;
    }
}

// ---------------- el/er directly from X ----------------
template<int V>
__global__ void compute_elr_v(const bf16* __restrict__ X, const float* __restrict__ wal,
                              const float* __restrict__ war, float* __restrict__ el,
                              float* __restrict__ er, int din) {
    typedef typename VecT<V>::type svec;
    int node = (blockIdx.x * blockDim.x + threadIdx.x) >> 6;
    int lane = threadIdx.x & 63;
    if (node >= NN) return;
    svec row = *(const svec*)((const short*)X + (long)node * din + lane * V);
    short tmp[V];
    __builtin_memcpy(tmp, &row, sizeof(row));
    float sl = 0.f, sr = 0.f;
    #pragma unroll
    for (int v = 0; v < V; v++) {
        float x = bfbits2f(tmp[v]);
        sl += x * wal[lane * V + v];
        sr += x * war[lane * V + v];
    }
    #pragma unroll
    for (int o = 32; o > 0; o >>= 1) {
        sl += __shfl_down(sl, o);
        sr += __shfl_down(sr, o);
    }
    if (lane == 0) { el[node] = sl; er[node] = sr; }
}

// ---------------- edge softmax per destination node ----------------
__global__ void edge_softmax(const int* __restrict__ off, const int* __restrict__ esrc,
                             const float* __restrict__ el, const float* __restrict__ er,
                             float* __restrict__ alpha, int n) {
    int d = blockIdx.x * blockDim.x + threadIdx.x;
    if (d >= n) return;
    int s = off[d], e = off[d + 1];
    if (e <= s) return;
    float erd = er[d];
    float mx = -1e30f;
    for (int j = s; j < e; j++) {
        float v = el[esrc[j]] + erd;
        v = v >= 0.f ? v : 0.2f * v;
        alpha[j] = v;
        mx = fmaxf(mx, v);
    }
    float ssum = 0.f;
    for (int j = s; j < e; j++) {
        float x = __expf(alpha[j] - mx);
        alpha[j] = x;
        ssum += x;
    }
    float inv = 1.f / ssum;
    for (int j = s; j < e; j++) alpha[j] *= inv;
}

// ---------------- Y = A @ X, din=64: wave per node ----------------
__global__ void aggregate_x1(const bf16* __restrict__ X, const float* __restrict__ alpha,
                             const int* __restrict__ esrc, const int* __restrict__ off,
                             bf16* __restrict__ Y, int din) {
    int node = blockIdx.x * (blockDim.x >> 6) + (threadIdx.x >> 6);
    if (node >= NN) return;
    int lane = threadIdx.x & 63;
    const short* xb = (const short*)X + lane;
    float acc = 0.f;
    int s = off[node], e = off[node + 1];
    float a_nx = 0.f; int r_nx = 0;
    if (s < e) { a_nx = alpha[s]; r_nx = esrc[s]; }
    for (int j = s; j < e; j++) {
        float a = a_nx; int r = r_nx;
        if (j + 1 < e) { a_nx = alpha[j + 1]; r_nx = esrc[j + 1]; }
        acc += a * bfbits2f(xb[(long)r * din]);
    }
    *((short*)Y + (long)node * din + lane) = f2bfbits(acc);
}

// ---------------- Y = A @ X, chunked: quarter-wave (16 lanes x 16B) per (node,chunk)
__global__ void aggregate_q(const bf16* __restrict__ X, const float* __restrict__ alpha,
                            const int* __restrict__ esrc, const int* __restrict__ off,
                            const int* __restrict__ perm, bf16* __restrict__ Y,
                            int din, int nodeBlocks) {
    int chunk = blockIdx.x / nodeBlocks;
    int nb = blockIdx.x - chunk * nodeBlocks;
    int qw = threadIdx.x >> 4, ql = threadIdx.x & 15;
    int slot = nb * 16 + qw;
    if (slot >= NN) return;
    int node = perm[slot];
    const short* xb = (const short*)X + chunk * 128 + ql * 8;
    float acc[8] = {0.f,0.f,0.f,0.f,0.f,0.f,0.f,0.f};
    int s = off[node], e = off[node + 1];
    float a_nx = 0.f; int r_nx = 0;
    if (s < e) { a_nx = alpha[s]; r_nx = esrc[s]; }
    for (int j = s; j < e; j++) {
        float a = a_nx; int r = r_nx;
        if (j + 1 < e) { a_nx = alpha[j + 1]; r_nx = esrc[j + 1]; }
        bf16x8 row = *(const bf16x8*)(xb + (long)r * din);
        #pragma unroll
        for (int v = 0; v < 8; v++) acc[v] += a * bfbits2f(row[v]);
    }
    short outv[8];
    #pragma unroll
    for (int v = 0; v < 8; v++) outv[v] = f2bfbits(acc[v]);
    bf16x8 store;
    __builtin_memcpy(&store, outv, sizeof(store));
    *(bf16x8*)((short*)Y + (long)node * din + chunk * 128 + ql * 8) = store;
}

// ---------------- tiled GEMM: X_next = tanh(Y @ W + b)
// 128x128 tile, BK=32, global_load_lds w16, XOR bank swizzle, XCD-aware block
// decode, LDS-staged coalesced epilogue. 4 blocks/CU.
__global__ __launch_bounds__(256, 4)
void gemm_tiled(const bf16* __restrict__ A, const bf16* __restrict__ WT,
                const float* __restrict__ bias, bf16* __restrict__ C,
                int M, int K, int N, int ncols, int nrows) {
    __shared__ short As[4096];      // 128 rows x 4 swizzled 16B slots
    __shared__ short Bs[4096];
    __shared__ short ep[9216];      // epilogue: 4 waves x 32 rows x stride 72
    // XCD-aware decode: all ncols col-tiles of a rowTile share blockIdx%8
    int g = blockIdx.x;
    int rowTile = ((g >> 3) / ncols) * 8 + (g & 7);
    int colTile = (g >> 3) % ncols;
    if (rowTile >= nrows) return;
    int row0 = rowTile << 7, col0 = colTile << 7;
    int tid = threadIdx.x;
    int lane = tid & 63, wave = tid >> 6;
    int wr = (wave >> 1) << 6;
    int wc = (wave & 1) << 6;
    int m = lane & 15, quad = lane >> 4;

    f32x4 acc[4][4];
    #pragma unroll
    for (int i = 0; i < 4; i++)
        #pragma unroll
        for (int j = 0; j < 4; j++) acc[i][j] = (f32x4){0.f, 0.f, 0.f, 0.f};

    // staging: slot t <-> (row = t>>2, kchunk q = (t&3) ^ ((row>>1)&3))
    int r1 = tid >> 2;
    int q1 = (tid & 3) ^ ((r1 >> 1) & 3);
    const short* Ab = (const short*)A;
    const short* Bb = (const short*)WT;
    long ga1 = (long)(row0 + r1) * K + q1 * 8;       // slot t
    long ga2 = ga1 + (long)64 * K;                   // slot t+256 (row+64, same q)
    long gb1 = (long)(col0 + r1) * K + q1 * 8;
    long gb2 = gb1 + (long)64 * K;

    typedef const __attribute__((address_space(1))) void cgvoid;
    typedef __attribute__((address_space(3))) void lvoid;

    for (int k0 = 0; k0 < K; k0 += 32) {
        __syncthreads();
        __builtin_amdgcn_global_load_lds((cgvoid*)(Ab + ga1 + k0), (lvoid*)(As + tid * 8),        16, 0, 0);
        __builtin_amdgcn_global_load_lds((cgvoid*)(Ab + ga2 + k0), (lvoid*)(As + 2048 + tid * 8), 16, 0, 0);
        __builtin_amdgcn_global_load_lds((cgvoid*)(Bb + gb1 + k0), (lvoid*)(Bs + tid * 8),        16, 0, 0);
        __builtin_amdgcn_global_load_lds((cgvoid*)(Bb + gb2 + k0), (lvoid*)(Bs + 2048 + tid * 8), 16, 0, 0);
        __syncthreads();
        bf16x8 af[4], bfr[4];
        #pragma unroll
        for (int s = 0; s < 4; s++) {
            int ra = wr + s * 16 + m;
            int sa = ra * 4 + (quad ^ ((ra >> 1) & 3));
            af[s] = *(const bf16x8*)(As + sa * 8);
            int rb = wc + s * 16 + m;
            int sb = rb * 4 + (quad ^ ((rb >> 1) & 3));
            bfr[s] = *(const bf16x8*)(Bs + sb * 8);
        }
        #pragma unroll
        for (int i = 0; i < 4; i++)
            #pragma unroll
            for (int j = 0; j < 4; j++)
                acc[i][j] = __builtin_amdgcn_mfma_f32_16x16x32_bf16(af[i], bfr[j], acc[i][j], 0, 0, 0);
    }

    // ---- epilogue: bias+tanh, pack pairs, LDS round-trip, b128 stores ----
    float bb[4];
    #pragma unroll
    for (int j = 0; j < 4; j++) bb[j] = bias[col0 + wc + j * 16 + m];
    short* myep = ep + wave * 2304;   // 32 rows x 72 shorts
    #pragma unroll
    for (int h = 0; h < 2; h++) {
        #pragma unroll
        for (int ii = 0; ii < 2; ii++) {
            int i = h * 2 + ii;
            #pragma unroll
            for (int j = 0; j < 4; j++) {
                #pragma unroll
                for (int r = 0; r < 4; r++) {
                    float v = tanhf(acc[i][j][r] + bb[j]);
                    float vn = __shfl_xor(v, 1);          // neighbor col's value
                    if ((m & 1) == 0) {
                        unsigned int pk = (unsigned int)f2bfu(v) |
                                          ((unsigned int)f2bfu(vn) << 16);
                        int lr = ii * 16 + quad * 4 + r;
                        *(unsigned int*)(myep + lr * 72 + j * 16 + m) = pk;
                    }
                }
            }
        }
        // readback: lane -> row pass*8 + lane>>3, 16B at col (lane&7)*8
        #pragma unroll
        for (int pass = 0; pass < 4; pass++) {
            int lr = pass * 8 + (lane >> 3);
            int lc = (lane & 7) * 8;
            bf16x8 v = *(const bf16x8*)(myep + lr * 72 + lc);
            int row = row0 + wr + h * 32 + lr;
            if (row < M)
                *(bf16x8*)((short*)C + (long)row * N + col0 + wc + lc) = v;
        }
    }
}

// ---------------- pool sum ----------------
__global__ void pool_sum(const bf16* __restrict__ X, const int* __restrict__ order,
                         float* __restrict__ poolsum) {
    int cg = blockIdx.x & 3, rs = blockIdx.x >> 2;
    int c = cg * 256 + threadIdx.x;
    int rows = order[0] + 1;
    float s = 0.f;
    for (int r = rs; r < rows; r += 64) s += b2f(X[(long)r * 1024 + c]);
    atomicAdd(&poolsum[c], s);
}

// ---------------- head ----------------
__global__ void head_logits(const float* __restrict__ poolsum, const float* __restrict__ relW,
                            const float* __restrict__ relB, const int* __restrict__ order,
                            float* __restrict__ logits) {
    int t = blockIdx.x;
    float s = 0.f;
    for (int c = threadIdx.x; c < 1024; c += 256)
        s += poolsum[c] * relW[(long)c * 64 + t];
    __shared__ float sb[256];
    sb[threadIdx.x] = s;
    __syncthreads();
    for (int st = 128; st > 0; st >>= 1) {
        if (threadIdx.x < st) sb[threadIdx.x] += sb[threadIdx.x + st];
        __syncthreads();
    }
    if (threadIdx.x == 0) {
        float rows = (float)(order[0] + 1);
        logits[t] = sb[0] / rows + relB[t];
    }
}

__global__ void head_gather(const float* __restrict__ logits, const int* __restrict__ rel,
                            float* __restrict__ out) {
    __shared__ int nzv[64];
    int t = threadIdx.x;
    if (t == 0) {
        int k = 0;
        for (int i = 0; i < 64; i++)
            if (rel[i] != 0) nzv[k++] = i;
        for (; k < 64; k++) nzv[k] = 0;
    }
    __syncthreads();
    out[t] = logits[nzv[t]];
}

extern "C" void kernel_launch(void* const* d_in, const int* in_sizes, int n_in,
                              void* d_out, int out_size, void* d_ws, size_t ws_size,
                              hipStream_t stream) {
    const float* feat = (const float*)d_in[0];
    const float* W[4]  = {(const float*)d_in[1], (const float*)d_in[5], (const float*)d_in[9],  (const float*)d_in[13]};
    const float* al[4] = {(const float*)d_in[2], (const float*)d_in[6], (const float*)d_in[10], (const float*)d_in[14]};
    const float* ar[4] = {(const float*)d_in[3], (const float*)d_in[7], (const float*)d_in[11], (const float*)d_in[15]};
    const float* bias[4] = {(const float*)d_in[4], (const float*)d_in[8], (const float*)d_in[12], (const float*)d_in[16]};
    const float* relW = (const float*)d_in[17];
    const float* relB = (const float*)d_in[18];
    const int* src = (const int*)d_in[19];
    const int* dst = (const int*)d_in[20];
    const int* rel = (const int*)d_in[21];
    const int* order = (const int*)d_in[22];

    const int dims[5] = {64, 128, 256, 512, 1024};

    char* p = (char*)d_ws;
    auto carve = [&](size_t bytes) {
        void* r = (void*)p;
        p += (bytes + 255) & ~(size_t)255;
        return r;
    };
    bf16* xbuf = (bf16*)carve((size_t)MPAD * 1024 * sizeof(bf16));
    bf16* ybuf = (bf16*)carve((size_t)MPAD * 512 * sizeof(bf16));
    bf16* featb = (bf16*)carve((size_t)MPAD * 64 * sizeof(bf16));
    bf16* wt[4];
    for (int l = 0; l < 4; l++)
        wt[l] = (bf16*)carve((size_t)dims[l] * dims[l + 1] * sizeof(bf16));
    float* walbuf = (float*)carve(4 * 512 * sizeof(float));
    float* warbuf = (float*)carve(4 * 512 * sizeof(float));
    float* el = (float*)carve((size_t)NN * sizeof(float));
    float* er = (float*)carve((size_t)NN * sizeof(float));
    float* alpha = (float*)carve((size_t)NE * sizeof(float));
    int* counts  = (int*)carve((size_t)NN * sizeof(int));
    int* offsets = (int*)carve((size_t)(NN + 1) * sizeof(int));
    int* cursor  = (int*)carve((size_t)NN * sizeof(int));
    int* esrc    = (int*)carve((size_t)NE * sizeof(int));
    int* nodeperm = (int*)carve((size_t)NN * sizeof(int));
    float* poolsum = (float*)carve(1024 * sizeof(float));
    float* logits  = (float*)carve(64 * sizeof(float));

    convert_f32_bf16<<<(NN * 64 + 255) / 256, 256, 0, stream>>>(feat, featb, NN * 64);
    for (int l = 0; l < 4; l++) {
        int ne = dims[l] * dims[l + 1];
        transpose_w<<<(ne + 255) / 256, 256, 0, stream>>>(W[l], wt[l], dims[l], dims[l + 1]);
        compute_walwar<<<dims[l], 256, 0, stream>>>(W[l], al[l], ar[l],
                                                    walbuf + l * 512, warbuf + l * 512, dims[l + 1]);
    }

    hipMemsetAsync(counts, 0, (size_t)NN * sizeof(int), stream);
    hist_kernel<<<(NE + 255) / 256, 256, 0, stream>>>(dst, counts, NE);
    scan_counts<<<1, 1024, 0, stream>>>(counts, offsets, cursor, NN);
    scatter_kernel<<<(NE + 255) / 256, 256, 0, stream>>>(src, dst, cursor, esrc, NE);
    degree_sort<<<1, 256, 0, stream>>>(counts, nodeperm);

    const bf16* x = featb;
    const int nodeBlocks = NN / 16;   // 1250
    const int nrows = MPAD / 128;     // 157
    const int nrowsPad = 160;         // padded to multiple of 8 for XCD decode
    for (int l = 0; l < 4; l++) {
        int K = dims[l], N = dims[l + 1];
        float* wal = walbuf + l * 512;
        float* war = warbuf + l * 512;
        switch (K) {
            case 64:  compute_elr_v<1><<<5000, 256, 0, stream>>>(x, wal, war, el, er, K); break;
            case 128: compute_elr_v<2><<<5000, 256, 0, stream>>>(x, wal, war, el, er, K); break;
            case 256: compute_elr_v<4><<<5000, 256, 0, stream>>>(x, wal, war, el, er, K); break;
            default:  compute_elr_v<8><<<5000, 256, 0, stream>>>(x, wal, war, el, er, K); break;
        }
        edge_softmax<<<(NN + 255) / 256, 256, 0, stream>>>(offsets, esrc, el, er, alpha, NN);
        if (K == 64) {
            aggregate_x1<<<5000, 256, 0, stream>>>(x, alpha, esrc, offsets, ybuf, K);
        } else {
            int chunks = K / 128;
            aggregate_q<<<chunks * nodeBlocks, 256, 0, stream>>>(x, alpha, esrc, offsets,
                                                                 nodeperm, ybuf, K, nodeBlocks);
        }
        int ncols = N >> 7;
        gemm_tiled<<<nrowsPad * ncols, 256, 0, stream>>>(ybuf, wt[l], bias[l], xbuf,
                                                         NN, K, N, ncols, nrows);
        x = xbuf;
    }

    hipMemsetAsync(poolsum, 0, 1024 * sizeof(float), stream);
    pool_sum<<<256, 256, 0, stream>>>(xbuf, order, poolsum);
    head_logits<<<64, 256, 0, stream>>>(poolsum, relW, relB, order, logits);
    head_gather<<<1, 64, 0, stream>>>(logits, rel, (float*)d_out);
}